// Round 2
// baseline (2356.488 us; speedup 1.0000x reference)
//
#include <hip/hip_runtime.h>

// FFT-based causal long convolution, (b=4, l=8192, d=1024) fp32.
// One workgroup per channel d; block loops over b (filter FFT hoisted).
// Real FFT of N=16384 via complex M=8192 packing. Forward: radix-2 DIF then
// 4x radix-8 DIF (natural -> digit-reversed). Inverse: mirrored DIT.
// LDS: exactly 64 KB, XOR-swizzled (i ^ ((i>>5)&15)) -> all stage accesses
// are <=4 lanes per float2-slot (the wave64 b64 minimum) = conflict-free.

#define M 8192
#define NTH 256
#define MAXP 17

#define LDSWZ(i) ((i) ^ (((i) >> 5) & 15))

__device__ __forceinline__ float2 cadd(float2 a, float2 b){ return make_float2(a.x+b.x, a.y+b.y); }
__device__ __forceinline__ float2 csub(float2 a, float2 b){ return make_float2(a.x-b.x, a.y-b.y); }
__device__ __forceinline__ float2 cmul(float2 a, float2 b){ return make_float2(a.x*b.x - a.y*b.y, a.x*b.y + a.y*b.x); }
__device__ __forceinline__ float2 conjf2(float2 a){ return make_float2(a.x, -a.y); }

static constexpr float PI_F = 3.14159265358979323846f;

// Position of frequency k after stage sequence [r2(h=4096), r8(512), r8(64), r8(8), r8(1)]
__device__ __forceinline__ int digitrev(int k) {
  return ((k & 1) << 12) | (((k >> 1) & 7) << 9) | (((k >> 4) & 7) << 6)
       | (((k >> 7) & 7) << 3) | ((k >> 10) & 7);
}

template<int S>  // multiply by S*i
__device__ __forceinline__ float2 mulSi(float2 z) {
  return (S > 0) ? make_float2(-z.y, z.x) : make_float2(z.y, -z.x);
}

// 8-point DFT, B_q = sum_t A_t * exp(S*2*pi*i*q*t/8). S=-1 fwd, S=+1 inv.
template<int S>
__device__ __forceinline__ void bfly8(float2 A[8]) {
  const float C0 = 0.70710678118654752440f;
  float2 s0 = cadd(A[0], A[4]), d0 = csub(A[0], A[4]);
  float2 s1 = cadd(A[1], A[5]), d1 = csub(A[1], A[5]);
  float2 s2 = cadd(A[2], A[6]), d2 = csub(A[2], A[6]);
  float2 s3 = cadd(A[3], A[7]), d3 = csub(A[3], A[7]);
  float2 E0 = cadd(s0, s2), E2 = csub(s0, s2);
  float2 id2 = mulSi<S>(d2);
  float2 E1 = cadd(d0, id2), E3 = csub(d0, id2);
  float2 O0 = cadd(s1, s3), O2 = csub(s1, s3);
  float2 id3 = mulSi<S>(d3);
  float2 O1 = cadd(d1, id3), O3 = csub(d1, id3);
  // w^S*O1 = c*((x-Sy) + i(y+Sx)); (Si)*O2; w^{3S}*O3 = c*(-(x+Sy) + i(Sx-y))
  float2 r1 = make_float2(C0 * (O1.x - S * O1.y), C0 * (O1.y + S * O1.x));
  float2 r2v = mulSi<S>(O2);
  float2 r3 = make_float2(-C0 * (O3.x + S * O3.y), C0 * (S * O3.x - O3.y));
  A[0] = cadd(E0, O0);  A[4] = csub(E0, O0);
  A[1] = cadd(E1, r1);  A[5] = csub(E1, r1);
  A[2] = cadd(E2, r2v); A[6] = csub(E2, r2v);
  A[3] = cadd(E3, r3);  A[7] = csub(E3, r3);
}

__device__ __forceinline__ void fwd_stage2(float2* L, int tid) {
#pragma unroll
  for (int p = 0; p < 16; ++p) {
    int j = tid + p * NTH;
    int i0 = LDSWZ(j), i1 = LDSWZ(j + 4096);
    float2 a = L[i0], b = L[i1];
    float s, c; __sincosf((-PI_F / 4096.f) * (float)j, &s, &c);
    L[i0] = cadd(a, b);
    L[i1] = cmul(csub(a, b), make_float2(c, s));
  }
  __syncthreads();
}

__device__ __forceinline__ void inv_stage2(float2* L, int tid) {
#pragma unroll
  for (int p = 0; p < 16; ++p) {
    int j = tid + p * NTH;
    int i0 = LDSWZ(j), i1 = LDSWZ(j + 4096);
    float s, c; __sincosf((PI_F / 4096.f) * (float)j, &s, &c);
    float2 a = L[i0];
    float2 b = cmul(L[i1], make_float2(c, s));
    L[i0] = cadd(a, b);
    L[i1] = csub(a, b);
  }
  __syncthreads();
}

template<bool TW, int H>
__device__ __forceinline__ void fwd_stage8(float2* L, int tid) {
#pragma unroll
  for (int p = 0; p < 4; ++p) {
    int idx = tid + p * NTH;
    int j = idx & (H - 1);
    int base = ((idx - j) << 3) + j;
    float2 A[8];
#pragma unroll
    for (int t = 0; t < 8; ++t) A[t] = L[LDSWZ(base + t * H)];
    bfly8<-1>(A);
    if (TW) {
      float s, c; __sincosf((-PI_F / (4.f * H)) * (float)j, &s, &c);
      float2 w1 = make_float2(c, s);
      float2 w2 = cmul(w1, w1);
      float2 w3 = cmul(w2, w1);
      float2 w4 = cmul(w2, w2);
      A[1] = cmul(A[1], w1);
      A[2] = cmul(A[2], w2);
      A[3] = cmul(A[3], w3);
      A[4] = cmul(A[4], w4);
      A[5] = cmul(A[5], cmul(w4, w1));
      A[6] = cmul(A[6], cmul(w4, w2));
      A[7] = cmul(A[7], cmul(w4, w3));
    }
#pragma unroll
    for (int t = 0; t < 8; ++t) L[LDSWZ(base + t * H)] = A[t];
  }
  __syncthreads();
}

template<bool TW, int H>
__device__ __forceinline__ void inv_stage8(float2* L, int tid) {
#pragma unroll
  for (int p = 0; p < 4; ++p) {
    int idx = tid + p * NTH;
    int j = idx & (H - 1);
    int base = ((idx - j) << 3) + j;
    float2 A[8];
#pragma unroll
    for (int t = 0; t < 8; ++t) A[t] = L[LDSWZ(base + t * H)];
    if (TW) {
      float s, c; __sincosf((PI_F / (4.f * H)) * (float)j, &s, &c);
      float2 w1 = make_float2(c, s);
      float2 w2 = cmul(w1, w1);
      float2 w3 = cmul(w2, w1);
      float2 w4 = cmul(w2, w2);
      A[1] = cmul(A[1], w1);
      A[2] = cmul(A[2], w2);
      A[3] = cmul(A[3], w3);
      A[4] = cmul(A[4], w4);
      A[5] = cmul(A[5], cmul(w4, w1));
      A[6] = cmul(A[6], cmul(w4, w2));
      A[7] = cmul(A[7], cmul(w4, w3));
    }
    bfly8<1>(A);
#pragma unroll
    for (int t = 0; t < 8; ++t) L[LDSWZ(base + t * H)] = A[t];
  }
  __syncthreads();
}

__device__ __forceinline__ void fwd_fft(float2* L, int tid) {
  fwd_stage2(L, tid);
  fwd_stage8<true, 512>(L, tid);
  fwd_stage8<true, 64>(L, tid);
  fwd_stage8<true, 8>(L, tid);
  fwd_stage8<false, 1>(L, tid);
}

__device__ __forceinline__ void inv_fft(float2* L, int tid) {
  inv_stage8<false, 1>(L, tid);
  inv_stage8<true, 8>(L, tid);
  inv_stage8<true, 64>(L, tid);
  inv_stage8<true, 512>(L, tid);
  inv_stage2(L, tid);
}

__global__ __launch_bounds__(NTH, 2)
void longconv_fft_kernel(const float* __restrict__ x,
                         const float* __restrict__ filt,
                         float* __restrict__ y) {
  __shared__ float2 L[M];                       // exactly 64 KB
  const int tid = threadIdx.x;

  // XCD swizzle: the 16 blocks covering d-group {16g..16g+15} share blk%8,
  // so one XCD's L2 assembles each 64B line of x/y (strided 4B accesses).
  const int blk  = blockIdx.x;
  const int xcd  = blk & 7;
  const int rest = blk >> 3;
  const int i16  = rest & 15;
  const int gg   = rest >> 4;
  const int g    = (gg << 3) | xcd;             // d-group in [0, 64)
  const int d    = (g << 4) | i16;              // channel in [0, 1024)

  // ---------------- Phase A: filter FFT (once per d) ----------------
  const float2* fp2 = (const float2*)(filt + (size_t)d * 8192);
#pragma unroll
  for (int p = 0; p < 16; ++p) {
    int m = tid + p * NTH;
    L[LDSWZ(m)] = fp2[m];
  }
#pragma unroll
  for (int p = 0; p < 16; ++p) {
    int m = 4096 + tid + p * NTH;
    L[LDSWZ(m)] = make_float2(0.f, 0.f);
  }
  __syncthreads();
  fwd_fft(L, tid);

  // rfft spectrum K[k], K[M-k] for k = tid + 256p, kept in registers.
  float2 Kk[MAXP], Kmk[MAXP];
#pragma unroll
  for (int p = 0; p < MAXP; ++p) {
    int k = tid + p * NTH;
    if (k <= M / 2) {
      float2 Zk  = L[LDSWZ(digitrev(k))];
      float2 Zmk = L[LDSWZ(digitrev((M - k) & (M - 1)))];
      float2 Ze = make_float2(0.5f * (Zk.x + Zmk.x), 0.5f * (Zk.y - Zmk.y));
      float2 Zo = make_float2(0.5f * (Zk.y + Zmk.y), 0.5f * (Zmk.x - Zk.x));
      float s, c; __sincosf((-PI_F / (float)M) * (float)k, &s, &c);
      float2 W = make_float2(c, s);
      float2 WZo = cmul(W, Zo);
      Kk[p]  = cadd(Ze, WZo);
      Kmk[p] = conjf2(csub(Ze, WZo));
    }
  }
  __syncthreads();

  // ---------------- Loop over batches ----------------
  for (int b = 0; b < 4; ++b) {
    const float* xp = x + (size_t)b * (8192 * 1024) + d;
#pragma unroll 4
    for (int p = 0; p < 16; ++p) {
      int m = tid + p * NTH;
      float v0 = xp[(size_t)(2 * m) * 1024];
      float v1 = xp[(size_t)(2 * m + 1) * 1024];
      L[LDSWZ(m)] = make_float2(v0, v1);
    }
#pragma unroll
    for (int p = 0; p < 16; ++p) {
      int m = 4096 + tid + p * NTH;
      L[LDSWZ(m)] = make_float2(0.f, 0.f);
    }
    __syncthreads();
    fwd_fft(L, tid);

    // unpack -> multiply -> repack, in place over (k, M-k) pairs
#pragma unroll
    for (int p = 0; p < MAXP; ++p) {
      int k = tid + p * NTH;
      if (k <= M / 2) {
        int pk  = LDSWZ(digitrev(k));
        int pmk = LDSWZ(digitrev((M - k) & (M - 1)));
        float2 Zk = L[pk], Zmk = L[pmk];
        float2 Ze = make_float2(0.5f * (Zk.x + Zmk.x), 0.5f * (Zk.y - Zmk.y));
        float2 Zo = make_float2(0.5f * (Zk.y + Zmk.y), 0.5f * (Zmk.x - Zk.x));
        float s, c; __sincosf((-PI_F / (float)M) * (float)k, &s, &c);
        float2 W = make_float2(c, s);
        float2 WZo = cmul(W, Zo);
        float2 Uk  = cadd(Ze, WZo);
        float2 Umk = conjf2(csub(Ze, WZo));
        float2 Yk  = cmul(Uk,  Kk[p]);
        float2 Ymk = cmul(Umk, Kmk[p]);
        float2 Ye  = make_float2(0.5f * (Yk.x + Ymk.x), 0.5f * (Yk.y - Ymk.y));
        float2 t2  = make_float2(0.5f * (Yk.x - Ymk.x), 0.5f * (Yk.y + Ymk.y));
        float2 Zoy = cmul(conjf2(W), t2);
        L[pk]  = make_float2(Ye.x - Zoy.y, Ye.y + Zoy.x);
        L[pmk] = make_float2(Ye.x + Zoy.y, Zoy.x - Ye.y);
      }
    }
    __syncthreads();
    inv_fft(L, tid);

    float* yp = y + (size_t)b * (8192 * 1024) + d;
    const float inv = 1.0f / (float)M;
#pragma unroll 4
    for (int p = 0; p < 16; ++p) {
      int m = tid + p * NTH;
      float2 v = L[LDSWZ(m)];
      yp[(size_t)(2 * m) * 1024]     = v.x * inv;
      yp[(size_t)(2 * m + 1) * 1024] = v.y * inv;
    }
    __syncthreads();   // stores read L; next iteration's loads overwrite it
  }
}

extern "C" void kernel_launch(void* const* d_in, const int* in_sizes, int n_in,
                              void* d_out, int out_size, void* d_ws, size_t ws_size,
                              hipStream_t stream) {
  const float* x    = (const float*)d_in[0];   // (b, l, d) fp32
  const float* filt = (const float*)d_in[1];   // (d, l) fp32
  float* y = (float*)d_out;                    // (b, l, d) fp32

  dim3 grid(1024), block(NTH);
  hipLaunchKernelGGL(longconv_fft_kernel, grid, block, 0, stream, x, filt, y);
}